// Round 18
// baseline (869.995 us; speedup 1.0000x reference)
//
#include <hip/hip_runtime.h>

// images (16,3,32,32) f32, kernel (2048,3,6,6) f32, bias (2048,) f32.
// out = (d < d_(128) per position) ? 1 : 0, d = [b-c, b-cf, c+b, cf+b].
// Selection = H3 AND H4 (proven: rounds 6,7,8,10,11,12,16,17 absmax 0.0;
// round-13 H4-only FAILED -> both load-bearing; intersection FROZEN).
// Bit-frozen accumulator sequences (each accumulator's own op order):
//   c3 : mul+add, k=(kh,kw,ci) ascending, weight w[ci][kh][kw]
//   cf3: mul+add, k=(kh,kw,ci) ascending, weight w[ci][kh][5-kw]
//   c4 : fmaf,    k=(kw,kh,ci) ascending, weight w[ci][kh][kw]
//   cf4: fmaf,    k=(kw,kh,ci) ascending, weight w[ci][kh][5-kw]
//
// Round-18: fused selection. sel_fused = round-17 thresh + post-bisection
// indicator computation + __ballot bit-pack (64 ch/word, bit==lane==ch&63).
// Bit-words are stored into the block's OWN Bp column (each Bp byte is read
// by exactly one block; 32 bisection barriers order reads before writes ->
// race-free, no extra ws). expand (structure = old writeout) reads 4 words/
// thread + writes out coalesced. Eliminates one full 382MB Bp read pass.

#define NPOS 729   // 27*27
#define NTHR 11664 // 16*729
#define FCH 16     // filters per conv block

__device__ __forceinline__ unsigned map32(float x) {
    unsigned v = __float_as_uint(x);
    return (v & 0x80000000u) ? ~v : (v | 0x80000000u);
}

// ---------------- prep: pad weights to 128-dword stride (natural order) ----------------
__global__ __launch_bounds__(128) void prep_w1(
    const float* __restrict__ wgt, float* __restrict__ s1)
{
    int f = blockIdx.x;
    int t = threadIdx.x;
    s1[f * 128 + t] = (t < 108) ? wgt[f * 108 + t] : 0.f;
}

// weight fetch: compile-time pos (<108), natural layout (ci*6+kh)*6+kw
#define RLW(pos) __int_as_float(__builtin_amdgcn_readlane(                      \
    ((pos) < 64 ? wv0 : wv1), (pos) & 63))
#define WIDX(ci, kh, kw) (((ci) * 6 + (kh)) * 6 + (kw))

// ---------------- conv: 1 pos/thread, H3+H4, shared readlanes ----------------
__global__ __launch_bounds__(256) void conv_rl34(
    const float* __restrict__ img, const float* __restrict__ s1,
    float4* __restrict__ Bp)
{
    // blockIdx.x = fg + 128*(pg + 3*n); 128 fgroups of FCH=16 filters
    int bx = blockIdx.x;
    int fg = bx & 127;
    int rest = bx >> 7;
    int pg = rest % 3;
    int n  = rest / 3;
    int t  = threadIdx.x;
    int lane = t & 63;

    bool act = t < 243;
    int p  = pg * 243 + (act ? t : 242);
    int oh = p / 27, ow = p % 27;

    float x[3][6][6];
    #pragma unroll
    for (int ci = 0; ci < 3; ci++)
        #pragma unroll
        for (int kh = 0; kh < 6; kh++)
            #pragma unroll
            for (int kw = 0; kw < 6; kw++)
                x[ci][kh][kw] = img[((n * 3 + ci) * 32 + oh + kh) * 32 + ow + kw];

    const int* sw = (const int*)s1;
    int f0 = fg * FCH;
    int wv0 = sw[f0 * 128 + lane];
    int wv1 = sw[f0 * 128 + 64 + lane];

    #pragma unroll 1
    for (int fi = 0; fi < FCH; fi++) {
        int f = f0 + fi;
        // prefetch next filter's weight dwords (register double-buffer)
        int nf = (fi == FCH - 1) ? f : (f + 1);
        int nv0 = sw[nf * 128 + lane];
        int nv1 = sw[nf * 128 + 64 + lane];

        float c3 = 0.f, cf3 = 0.f, c4 = 0.f, cf4 = 0.f;

        // H3: c3/cf3, each chain (kh,kw,ci) ascending — verbatim sequences
        #pragma unroll
        for (int kh = 0; kh < 6; kh++)
            #pragma unroll
            for (int kw = 0; kw < 6; kw++)
                #pragma unroll
                for (int ci = 0; ci < 3; ci++) {
                    float wa = RLW(WIDX(ci, kh, kw));
                    float wb = RLW(WIDX(ci, kh, 5 - kw));
                    float xx = x[ci][kh][kw];
                    c3  = __fadd_rn(c3,  __fmul_rn(wa, xx));
                    cf3 = __fadd_rn(cf3, __fmul_rn(wb, xx));
                }

        // H4: c4/cf4, each chain (kw,kh,ci) ascending — verbatim sequences
        #pragma unroll
        for (int kw = 0; kw < 6; kw++)
            #pragma unroll
            for (int kh = 0; kh < 6; kh++)
                #pragma unroll
                for (int ci = 0; ci < 3; ci++) {
                    float wa = RLW(WIDX(ci, kh, kw));
                    float wb = RLW(WIDX(ci, kh, 5 - kw));
                    float xx = x[ci][kh][kw];
                    c4  = fmaf(wa, xx, c4);
                    cf4 = fmaf(wb, xx, cf4);
                }

        if (act)
            Bp[((long)n * 2048 + f) * NPOS + p] = make_float4(c3, cf3, c4, cf4);
        wv0 = nv0; wv1 = nv1;
    }
}

// ---------------- sel_fused: bisect + indicators + ballot bit-pack ----------------
// Min-key pruning valid: every tested cutoff stays below key(0) (the kth
// value is deep-negative) and max(b±c) = b+|c| >= 0, so counts over the
// 4096 min-keys equal counts over all 8192 d-values (per hypothesis).
// Bit-words land in the block's own (already fully read) Bp column:
//   word widx of position (n,p) -> 8B at float4 slot Bp[(n*2048+widx)*NPOS+p]
__global__ __launch_bounds__(256) void sel_fused(
    float4* __restrict__ Bp, const float* __restrict__ bias)
{
    // XCD swizzle: consecutive p share an XCD L2 (11664 = 8*1458, bijective)
    int bx = blockIdx.x;
    int w  = (bx & 7) * 1458 + (bx >> 3);
    int n = w / NPOS;
    int p = w % NPOS;
    int t = threadIdx.x;
    int lane = t & 63, wid = t >> 6;

    float4 v[8];
    float  bb[8];
    unsigned m3[2][8], m4[2][8];
    #pragma unroll
    for (int j = 0; j < 8; j++) {
        int f = t + 256 * j;
        v[j]  = Bp[((long)n * 2048 + f) * NPOS + p];
        bb[j] = bias[f];
        float b = bb[j];
        m3[0][j] = min(map32(__fsub_rn(b, v[j].x)), map32(__fadd_rn(v[j].x, b)));
        m3[1][j] = min(map32(__fsub_rn(b, v[j].y)), map32(__fadd_rn(v[j].y, b)));
        m4[0][j] = min(map32(__fsub_rn(b, v[j].z)), map32(__fadd_rn(v[j].z, b)));
        m4[1][j] = min(map32(__fsub_rn(b, v[j].w)), map32(__fadd_rn(v[j].w, b)));
    }

    __shared__ int partial[2][4];   // parity-buffered -> 1 barrier/round
    unsigned P3 = 0, P4 = 0;
    #pragma unroll 1
    for (int bit = 31; bit >= 0; bit--) {
        unsigned C3 = P3 | (1u << bit);
        unsigned C4 = P4 | (1u << bit);
        int cnt = 0;                // low 16: H3 count, high 16: H4 count
        #pragma unroll
        for (int k = 0; k < 2; k++)
        #pragma unroll
        for (int j = 0; j < 8; j++) {
            cnt += (m3[k][j] < C3) ? 1 : 0;
            cnt += (m4[k][j] < C4) ? (1 << 16) : 0;
        }
        #pragma unroll
        for (int off = 32; off >= 1; off >>= 1) cnt += __shfl_xor(cnt, off, 64);
        int par = bit & 1;
        if (lane == 0) partial[par][wid] = cnt;
        __syncthreads();
        int tot = partial[par][0] + partial[par][1] + partial[par][2] + partial[par][3];
        if ((tot & 0xFFFF) <= 128) P3 = C3;   // count(u<C)<=128 => u_(128)>=C
        if ((tot >> 16)    <= 128) P4 = C4;
    }

    // indicators -> ballot words (ch = q*2048 + 256j + 64*wid + lane; bit==lane)
    unsigned long long* bw = (unsigned long long*)Bp;
    long cb = ((long)n * 2048) * NPOS + p;   // float4-slot index base (widx term added below)
    #pragma unroll
    for (int j = 0; j < 8; j++) {
        float b = bb[j];
        int s0 = (map32(__fsub_rn(b, v[j].x)) < P3) && (map32(__fsub_rn(b, v[j].z)) < P4);
        int s1 = (map32(__fsub_rn(b, v[j].y)) < P3) && (map32(__fsub_rn(b, v[j].w)) < P4);
        int s2 = (map32(__fadd_rn(v[j].x, b)) < P3) && (map32(__fadd_rn(v[j].z, b)) < P4);
        int s3 = (map32(__fadd_rn(v[j].y, b)) < P3) && (map32(__fadd_rn(v[j].w, b)) < P4);
        unsigned long long w0 = __ballot(s0);
        unsigned long long w1 = __ballot(s1);
        unsigned long long w2 = __ballot(s2);
        unsigned long long w3 = __ballot(s3);
        if (lane == 0) {
            int wbase = 4 * j + wid;                 // widx = q*32 + 4j + wid
            bw[(cb + (long)(wbase      ) * NPOS) * 2] = w0;
            bw[(cb + (long)(wbase + 32 ) * NPOS) * 2] = w1;
            bw[(cb + (long)(wbase + 64 ) * NPOS) * 2] = w2;
            bw[(cb + (long)(wbase + 96 ) * NPOS) * 2] = w3;
        }
    }
}

// ---------------- expand: read bit-words, write out coalesced ----------------
__global__ __launch_bounds__(256) void expand(
    const float4* __restrict__ Bp, float* __restrict__ out)
{
    // blockIdx.x = grp + 3*(ftile + 32*n); wave w covers p-segment grp*4+w
    int bx = blockIdx.x;
    int grp = bx % 3;
    int rest = bx / 3;
    int ftile = rest & 31;
    int n = rest >> 5;
    int t = threadIdx.x;
    int w = t >> 6, lane = t & 63;
    int p = (grp * 4 + w) * 64 + lane;
    bool act = p < NPOS;
    int pc = act ? p : (NPOS - 1);

    const unsigned long long* bw = (const unsigned long long*)Bp;
    long cb = ((long)n * 2048) * NPOS + pc;
    unsigned long long w0 = bw[(cb + (long)(ftile      ) * NPOS) * 2];
    unsigned long long w1 = bw[(cb + (long)(ftile + 32 ) * NPOS) * 2];
    unsigned long long w2 = bw[(cb + (long)(ftile + 64 ) * NPOS) * 2];
    unsigned long long w3 = bw[(cb + (long)(ftile + 96 ) * NPOS) * 2];

    long nb = (long)n * 8192 * NPOS;
    #pragma unroll 1
    for (int fi = 0; fi < 64; fi++) {
        int f = ftile * 64 + fi;
        if (act) {
            out[nb + (long)(f       ) * NPOS + p] = ((w0 >> fi) & 1) ? 1.0f : 0.0f;
            out[nb + (long)(f + 2048) * NPOS + p] = ((w1 >> fi) & 1) ? 1.0f : 0.0f;
            out[nb + (long)(f + 4096) * NPOS + p] = ((w2 >> fi) & 1) ? 1.0f : 0.0f;
            out[nb + (long)(f + 6144) * NPOS + p] = ((w3 >> fi) & 1) ? 1.0f : 0.0f;
        }
    }
}

// ---------------- fallback: round-6 proven kernels (no ws) ----------------
__global__ __launch_bounds__(256) void conv_h34(
    const float* __restrict__ img, const float* __restrict__ wgt,
    float* __restrict__ out)
{
    int bx = blockIdx.x;
    int ftile = bx & 31;
    int rest  = bx >> 5;
    int oh = rest % 27;
    int n  = rest / 27;
    int t  = threadIdx.x;

    __shared__ float wl[64][109];
    __shared__ float patch[3][6][32];
    for (int idx = t; idx < 64 * 108; idx += 256) {
        int fi = idx / 108, k = idx - fi * 108;
        wl[fi][k] = wgt[(ftile * 64 + fi) * 108 + k];
    }
    for (int idx = t; idx < 576; idx += 256) {
        int w = idx & 31, rr = idx >> 5;
        int ci = rr / 6, r = rr - ci * 6;
        patch[ci][r][w] = img[((n * 3 + ci) * 32 + (oh + r)) * 32 + w];
    }
    __syncthreads();

    int fidx = t & 63;
    int g    = t >> 6;
    int ow0  = g * 7;
    int ncols = (g < 3) ? 7 : 6;
    int f = ftile * 64 + fidx;
    long nb = (long)n * 8192 * NPOS;
    long pb = (long)oh * 27;

    #pragma unroll 1
    for (int i = 0; i < ncols; i++) {
        int ow = ow0 + i;
        float c3 = 0, cf3 = 0, c4 = 0, cf4 = 0;
        #pragma unroll
        for (int kh = 0; kh < 6; kh++)
        #pragma unroll
        for (int kw = 0; kw < 6; kw++)
        #pragma unroll
        for (int ci = 0; ci < 3; ci++) {
            float x = patch[ci][kh][ow + kw];
            c3  = __fadd_rn(c3,  __fmul_rn(wl[fidx][(ci*6+kh)*6 + kw],     x));
            cf3 = __fadd_rn(cf3, __fmul_rn(wl[fidx][(ci*6+kh)*6 + 5 - kw], x));
        }
        #pragma unroll
        for (int kw = 0; kw < 6; kw++)
        #pragma unroll
        for (int kh = 0; kh < 6; kh++)
        #pragma unroll
        for (int ci = 0; ci < 3; ci++) {
            float x = patch[ci][kh][ow + kw];
            c4  = fmaf(wl[fidx][(ci*6+kh)*6 + kw],     x, c4);
            cf4 = fmaf(wl[fidx][(ci*6+kh)*6 + 5 - kw], x, cf4);
        }
        long pp = pb + ow;
        out[nb + (long)(f       ) * NPOS + pp] = c3;
        out[nb + (long)(f + 2048) * NPOS + pp] = cf3;
        out[nb + (long)(f + 4096) * NPOS + pp] = c4;
        out[nb + (long)(f + 6144) * NPOS + pp] = cf4;
    }
}

__device__ __forceinline__ unsigned bisect128(const unsigned (&u)[4][8],
                                              int lane, int wid, int* partial)
{
    unsigned P = 0;
    #pragma unroll 1
    for (int bit = 31; bit >= 0; bit--) {
        unsigned C = P | (1u << bit);
        int cnt = 0;
        #pragma unroll
        for (int q = 0; q < 4; q++)
            #pragma unroll
            for (int j = 0; j < 8; j++) cnt += (u[q][j] < C) ? 1 : 0;
        #pragma unroll
        for (int off = 32; off >= 1; off >>= 1) cnt += __shfl_xor(cnt, off, 64);
        if (lane == 0) partial[wid] = cnt;
        __syncthreads();
        int tot = partial[0] + partial[1] + partial[2] + partial[3];
        __syncthreads();
        if (tot <= 128) P = C;
    }
    return P;
}

__global__ __launch_bounds__(256) void sel_h34(
    const float* __restrict__ bias, float* out)
{
    int bx = blockIdx.x;
    int n = bx / NPOS;
    int p = bx % NPOS;
    int t = threadIdx.x;
    int lane = t & 63, wid = t >> 6;
    __shared__ int partial[4];

    unsigned u3[4][8], u4[4][8];
    long nb = (long)n * 8192 * NPOS;
    #pragma unroll
    for (int j = 0; j < 8; j++) {
        int f = t + 256 * j;
        float c3  = out[nb + (long)(f       ) * NPOS + p];
        float cf3 = out[nb + (long)(f + 2048) * NPOS + p];
        float c4  = out[nb + (long)(f + 4096) * NPOS + p];
        float cf4 = out[nb + (long)(f + 6144) * NPOS + p];
        float b   = bias[f];
        u3[0][j] = map32(__fsub_rn(b, c3));
        u3[1][j] = map32(__fsub_rn(b, cf3));
        u3[2][j] = map32(__fadd_rn(c3, b));
        u3[3][j] = map32(__fadd_rn(cf3, b));
        u4[0][j] = map32(__fsub_rn(b, c4));
        u4[1][j] = map32(__fsub_rn(b, cf4));
        u4[2][j] = map32(__fadd_rn(c4, b));
        u4[3][j] = map32(__fadd_rn(cf4, b));
    }
    unsigned P3 = bisect128(u3, lane, wid, partial);
    unsigned P4 = bisect128(u4, lane, wid, partial);
    #pragma unroll
    for (int j = 0; j < 8; j++) {
        int f = t + 256 * j;
        #pragma unroll
        for (int q = 0; q < 4; q++) {
            int s = (u3[q][j] < P3) && (u4[q][j] < P4);
            out[nb + (long)(q * 2048 + f) * NPOS + p] = s ? 1.0f : 0.0f;
        }
    }
}

extern "C" void kernel_launch(void* const* d_in, const int* in_sizes, int n_in,
                              void* d_out, int out_size, void* d_ws, size_t ws_size,
                              hipStream_t stream)
{
    const float* img  = (const float*)d_in[0];
    const float* wgt  = (const float*)d_in[1];
    const float* bias = (const float*)d_in[2];
    float* out = (float*)d_out;

    size_t bpB  = (size_t)16 * 2048 * NPOS * sizeof(float4);   // 382,205,952
    size_t s1B  = (size_t)2048 * 128 * sizeof(float);          //   1,048,576
    size_t need = bpB + s1B;                                    // 383,254,528

    if (ws_size >= need) {
        float4* Bp = (float4*)d_ws;
        float*  s1 = (float*)((char*)d_ws + bpB);
        prep_w1<<<2048, 128, 0, stream>>>(wgt, s1);
        conv_rl34<<<128 * 3 * 16, 256, 0, stream>>>(img, s1, Bp);
        sel_fused<<<NTHR, 256, 0, stream>>>(Bp, bias);
        expand<<<16 * 32 * 3, 256, 0, stream>>>(Bp, out);
    } else {
        conv_h34<<<16 * 27 * 32, 256, 0, stream>>>(img, wgt, out);
        sel_h34<<<NTHR, 256, 0, stream>>>(bias, out);
    }
}